// Round 1
// baseline (66.762 us; speedup 1.0000x reference)
//
#include <hip/hip_runtime.h>

#define FIN   1024
#define FOUT2 1024
#define NTASK 20
#define BSZ   256
#define MCH   16                 // samples staged per chunk
#define HOFF  (256 * 512)        // h output elements before logits

// Grid: NTASK * 64 blocks. Block b -> task (b>>6), output tile (b&63) of 16 outputs.
// Each block: build stable list of samples with this task (ballot/popcount),
// stage up to MCH x-rows in LDS, stream W rows once (coalesced float4),
// accumulate per-sample dots in registers, butterfly-reduce, write logits + h.
__global__ __launch_bounds__(256, 2)
void cond_linear_kernel(const float* __restrict__ x,
                        const int* __restrict__ task_id,
                        const float* __restrict__ W,
                        float* __restrict__ out) {
    __shared__ float xs[MCH][FIN];       // 64 KB
    __shared__ int   sh_ord[BSZ];
    __shared__ int   wcnt[4];
    __shared__ int   sh_n;

    const int tid  = threadIdx.x;
    const int lane = tid & 63;
    const int wv   = tid >> 6;
    const int t      = blockIdx.x >> 6;   // task id
    const int tile   = blockIdx.x & 63;   // 64 tiles of 16 outputs
    const int o_base = tile * 16;

    // ---- build this task's stable sample list (B == blockDim == 256) ----
    const int my_task = task_id[tid];
    const bool match = (my_task == t);
    const unsigned long long m64 = __ballot(match);
    if (lane == 0) wcnt[wv] = __popcll(m64);
    __syncthreads();
    int base = 0;
    #pragma unroll
    for (int w = 0; w < 4; ++w)
        if (w < wv) base += wcnt[w];
    if (match) {
        const int pos = base + __popcll(m64 & ((1ull << lane) - 1ull));
        sh_ord[pos] = tid;
    }
    if (tid == 0) sh_n = wcnt[0] + wcnt[1] + wcnt[2] + wcnt[3];
    __syncthreads();
    const int n = sh_n;
    if (n == 0) return;

    const float* Wt = W + (size_t)t * (FOUT2 * FIN);

    for (int c0 = 0; c0 < n; c0 += MCH) {
        const int M = min(MCH, n - c0);

        // ---- stage M x-rows into LDS (coalesced: 256 float4 per row) ----
        for (int m = 0; m < M; ++m) {
            const int s = sh_ord[c0 + m];
            ((float4*)xs[m])[tid] = ((const float4*)(x + (size_t)s * FIN))[tid];
        }
        __syncthreads();

        // ---- each wave: 2 output pairs; W rows streamed once, coalesced ----
        #pragma unroll
        for (int pr = 0; pr < 2; ++pr) {
            const int o0 = o_base + wv * 4 + pr * 2;
            const float4* w0 = (const float4*)(Wt + (size_t)o0 * FIN);
            const float4* w1 = (const float4*)(Wt + (size_t)(o0 + 1) * FIN);

            float acc0[MCH], acc1[MCH];
            #pragma unroll
            for (int m = 0; m < MCH; ++m) { acc0[m] = 0.f; acc1[m] = 0.f; }

            #pragma unroll
            for (int p = 0; p < 4; ++p) {
                const float4 a = w0[p * 64 + lane];
                const float4 b = w1[p * 64 + lane];
                #pragma unroll
                for (int m = 0; m < MCH; ++m) {
                    if (m < M) {
                        const float4 xv = ((const float4*)xs[m])[p * 64 + lane];
                        acc0[m] += a.x * xv.x + a.y * xv.y + a.z * xv.z + a.w * xv.w;
                        acc1[m] += b.x * xv.x + b.y * xv.y + b.z * xv.z + b.w * xv.w;
                    }
                }
            }

            #pragma unroll
            for (int m = 0; m < MCH; ++m) {
                if (m < M) {
                    float r0 = acc0[m], r1 = acc1[m];
                    #pragma unroll
                    for (int sh = 32; sh >= 1; sh >>= 1) {
                        r0 += __shfl_xor(r0, sh, 64);
                        r1 += __shfl_xor(r1, sh, 64);
                    }
                    if (lane == 0) {
                        const int s = sh_ord[c0 + m];
                        out[HOFF + (size_t)s * FOUT2 + o0]     = r0;
                        out[HOFF + (size_t)s * FOUT2 + o0 + 1] = r1;
                        out[(size_t)s * (FOUT2 / 2) + (o0 >> 1)] = (r0 >= r1) ? 1.0f : 0.0f;
                    }
                }
            }
        }
        __syncthreads();   // xs reused next chunk
    }
}

extern "C" void kernel_launch(void* const* d_in, const int* in_sizes, int n_in,
                              void* d_out, int out_size, void* d_ws, size_t ws_size,
                              hipStream_t stream) {
    const float* x       = (const float*)d_in[0];
    const int*   task_id = (const int*)d_in[1];
    const float* W       = (const float*)d_in[2];
    float*       out     = (float*)d_out;

    dim3 grid(NTASK * 64);
    dim3 block(BSZ);
    hipLaunchKernelGGL(cond_linear_kernel, grid, block, 0, stream,
                       x, task_id, W, out);
}

// Round 2
// 49.753 us; speedup vs baseline: 1.3419x; 1.3419x over previous
//
#include <hip/hip_runtime.h>

#define FIN   1024
#define FOUT2 1024
#define NTASK 20
#define BSZ   256
#define MCH   8                  // samples staged per chunk (32 KB LDS -> 4 blocks/CU)
#define HOFF  (256 * 512)        // h output elements before logits

// Grid: NTASK * 64 blocks. Block b -> task (b>>6), output tile (b&63) of 16 outputs.
// Each block: build stable sample list (ballot/popcount), hoist its wave's 4 W rows
// into registers ONCE, then per 8-sample chunk: stage x rows in LDS, accumulate
// 4 rows x 8 samples in registers, butterfly-reduce, write logits + h.
// Numerics (dot order, butterfly order) identical to the round-1 passing kernel.
__global__ __launch_bounds__(256, 4)
void cond_linear_kernel(const float* __restrict__ x,
                        const int* __restrict__ task_id,
                        const float* __restrict__ W,
                        float* __restrict__ out) {
    __shared__ float xs[MCH][FIN];       // 32 KB
    __shared__ int   sh_ord[BSZ];
    __shared__ int   wcnt[4];
    __shared__ int   sh_n;

    const int tid  = threadIdx.x;
    const int lane = tid & 63;
    const int wv   = tid >> 6;
    const int t      = blockIdx.x >> 6;   // task id
    const int tile   = blockIdx.x & 63;   // 64 tiles of 16 outputs
    const int o0     = tile * 16 + wv * 4;  // this wave's 4 output rows

    // ---- build this task's stable sample list (B == blockDim == 256) ----
    const int my_task = task_id[tid];
    const bool match = (my_task == t);
    const unsigned long long m64 = __ballot(match);
    if (lane == 0) wcnt[wv] = __popcll(m64);
    __syncthreads();
    int base = 0;
    #pragma unroll
    for (int w = 0; w < 4; ++w)
        if (w < wv) base += wcnt[w];
    if (match) {
        const int pos = base + __popcll(m64 & ((1ull << lane) - 1ull));
        sh_ord[pos] = tid;
    }
    if (tid == 0) sh_n = wcnt[0] + wcnt[1] + wcnt[2] + wcnt[3];
    __syncthreads();
    const int n = sh_n;
    if (n == 0) return;

    // ---- hoist this wave's 4 W rows into registers (read W exactly once) ----
    const float* Wt = W + (size_t)t * (FOUT2 * FIN);
    float4 wr[4][4];
    #pragma unroll
    for (int r = 0; r < 4; ++r) {
        const float4* wp = (const float4*)(Wt + (size_t)(o0 + r) * FIN);
        #pragma unroll
        for (int p = 0; p < 4; ++p)
            wr[r][p] = wp[p * 64 + lane];
    }

    for (int c0 = 0; c0 < n; c0 += MCH) {
        const int M = min(MCH, n - c0);

        // ---- stage M x-rows into LDS (coalesced: 256 float4 per row) ----
        for (int m = 0; m < M; ++m) {
            const int s = sh_ord[c0 + m];
            ((float4*)xs[m])[tid] = ((const float4*)(x + (size_t)s * FIN))[tid];
        }
        __syncthreads();

        // ---- 4 rows x 8 samples in registers; xv reused 4x per LDS read ----
        float acc[4][MCH];
        #pragma unroll
        for (int r = 0; r < 4; ++r)
            #pragma unroll
            for (int m = 0; m < MCH; ++m) acc[r][m] = 0.f;

        #pragma unroll
        for (int p = 0; p < 4; ++p) {
            #pragma unroll
            for (int m = 0; m < MCH; ++m) {
                if (m < M) {
                    const float4 xv = ((const float4*)xs[m])[p * 64 + lane];
                    #pragma unroll
                    for (int r = 0; r < 4; ++r) {
                        acc[r][m] += wr[r][p].x * xv.x + wr[r][p].y * xv.y
                                   + wr[r][p].z * xv.z + wr[r][p].w * xv.w;
                    }
                }
            }
        }

        // ---- butterfly reduce (same 32..1 order as round 1), lane 0 writes ----
        #pragma unroll
        for (int m = 0; m < MCH; ++m) {
            if (m < M) {
                float v0 = acc[0][m], v1 = acc[1][m], v2 = acc[2][m], v3 = acc[3][m];
                #pragma unroll
                for (int sh = 32; sh >= 1; sh >>= 1) {
                    v0 += __shfl_xor(v0, sh, 64);
                    v1 += __shfl_xor(v1, sh, 64);
                    v2 += __shfl_xor(v2, sh, 64);
                    v3 += __shfl_xor(v3, sh, 64);
                }
                if (lane == 0) {
                    const int s = sh_ord[c0 + m];
                    float* lo = out + HOFF + (size_t)s * FOUT2 + o0;
                    lo[0] = v0; lo[1] = v1; lo[2] = v2; lo[3] = v3;
                    out[(size_t)s * (FOUT2 / 2) + (o0 >> 1)]     = (v0 >= v1) ? 1.0f : 0.0f;
                    out[(size_t)s * (FOUT2 / 2) + (o0 >> 1) + 1] = (v2 >= v3) ? 1.0f : 0.0f;
                }
            }
        }
        __syncthreads();   // xs reused next chunk
    }
}

extern "C" void kernel_launch(void* const* d_in, const int* in_sizes, int n_in,
                              void* d_out, int out_size, void* d_ws, size_t ws_size,
                              hipStream_t stream) {
    const float* x       = (const float*)d_in[0];
    const int*   task_id = (const int*)d_in[1];
    const float* W       = (const float*)d_in[2];
    float*       out     = (float*)d_out;

    dim3 grid(NTASK * 64);
    dim3 block(BSZ);
    hipLaunchKernelGGL(cond_linear_kernel, grid, block, 0, stream,
                       x, task_id, W, out);
}

// Round 3
// 46.262 us; speedup vs baseline: 1.4431x; 1.0755x over previous
//
#include <hip/hip_runtime.h>

#define FIN   1024
#define FOUT2 1024
#define NTASK 20
#define BSZ   256
#define MCH   8                  // samples per chunk (32 KB LDS -> 4 blocks/CU)
#define CSLOT 3                  // chunk-slots per (task,tile)
#define HOFF  (256 * 512)        // h output elements before logits

// Grid: NTASK * 64 * CSLOT blocks. Block -> (task, 16-output tile, chunk slot).
// Slot s processes sample-chunks s, s+CSLOT, ... (typically exactly one chunk,
// often zero -> early exit before touching W). Per-(row,sample) math and the
// 64-lane butterfly are bit-identical to the round-1/2 passing kernels.
__global__ __launch_bounds__(256, 4)
void cond_linear_kernel(const float* __restrict__ x,
                        const int* __restrict__ task_id,
                        const float* __restrict__ W,
                        float* __restrict__ out) {
    __shared__ float xs[MCH][FIN];       // 32 KB
    __shared__ int   sh_ord[BSZ];
    __shared__ int   wcnt[4];
    __shared__ int   sh_n;

    const int tid  = threadIdx.x;
    const int lane = tid & 63;
    const int wv   = tid >> 6;

    const int bx   = blockIdx.x;
    const int t    = bx / (64 * CSLOT);
    const int rem  = bx % (64 * CSLOT);
    const int tile = rem / CSLOT;
    const int slot = rem % CSLOT;
    const int o0   = tile * 16 + wv * 4;  // this wave's 4 output rows

    // ---- build this task's stable sample list (B == blockDim == 256) ----
    const int my_task = task_id[tid];
    const bool match = (my_task == t);
    const unsigned long long m64 = __ballot(match);
    if (lane == 0) wcnt[wv] = __popcll(m64);
    __syncthreads();
    int base = 0;
    #pragma unroll
    for (int w = 0; w < 4; ++w)
        if (w < wv) base += wcnt[w];
    if (match) {
        const int pos = base + __popcll(m64 & ((1ull << lane) - 1ull));
        sh_ord[pos] = tid;
    }
    if (tid == 0) sh_n = wcnt[0] + wcnt[1] + wcnt[2] + wcnt[3];
    __syncthreads();
    const int n = sh_n;
    if (slot * MCH >= n) return;          // no chunk for this slot

    // ---- this wave's 4 W rows (read once per block; L2/L3 serves re-reads) ----
    const float* Wt = W + (size_t)t * (FOUT2 * FIN);
    float4 wr[4][4];
    #pragma unroll
    for (int r = 0; r < 4; ++r) {
        const float4* wp = (const float4*)(Wt + (size_t)(o0 + r) * FIN);
        #pragma unroll
        for (int p = 0; p < 4; ++p)
            wr[r][p] = wp[p * 64 + lane];
    }

    for (int c0 = slot * MCH; c0 < n; c0 += CSLOT * MCH) {
        const int M = min(MCH, n - c0);

        // ---- stage M x-rows into LDS (coalesced: 256 float4 per row) ----
        for (int m = 0; m < M; ++m) {
            const int s = sh_ord[c0 + m];
            ((float4*)xs[m])[tid] = ((const float4*)(x + (size_t)s * FIN))[tid];
        }
        __syncthreads();

        // ---- 4 rows x 8 samples in registers; xv reused 4x per LDS read ----
        float acc[4][MCH];
        #pragma unroll
        for (int r = 0; r < 4; ++r)
            #pragma unroll
            for (int m = 0; m < MCH; ++m) acc[r][m] = 0.f;

        #pragma unroll
        for (int p = 0; p < 4; ++p) {
            #pragma unroll
            for (int m = 0; m < MCH; ++m) {
                if (m < M) {
                    const float4 xv = ((const float4*)xs[m])[p * 64 + lane];
                    #pragma unroll
                    for (int r = 0; r < 4; ++r) {
                        acc[r][m] += wr[r][p].x * xv.x + wr[r][p].y * xv.y
                                   + wr[r][p].z * xv.z + wr[r][p].w * xv.w;
                    }
                }
            }
        }

        // ---- butterfly reduce (same 32..1 order), lane 0 writes ----
        #pragma unroll
        for (int m = 0; m < MCH; ++m) {
            if (m < M) {
                float v0 = acc[0][m], v1 = acc[1][m], v2 = acc[2][m], v3 = acc[3][m];
                #pragma unroll
                for (int sh = 32; sh >= 1; sh >>= 1) {
                    v0 += __shfl_xor(v0, sh, 64);
                    v1 += __shfl_xor(v1, sh, 64);
                    v2 += __shfl_xor(v2, sh, 64);
                    v3 += __shfl_xor(v3, sh, 64);
                }
                if (lane == 0) {
                    const int s = sh_ord[c0 + m];
                    float* lo = out + HOFF + (size_t)s * FOUT2 + o0;
                    lo[0] = v0; lo[1] = v1; lo[2] = v2; lo[3] = v3;
                    out[(size_t)s * (FOUT2 / 2) + (o0 >> 1)]     = (v0 >= v1) ? 1.0f : 0.0f;
                    out[(size_t)s * (FOUT2 / 2) + (o0 >> 1) + 1] = (v2 >= v3) ? 1.0f : 0.0f;
                }
            }
        }
        __syncthreads();   // xs reused next chunk (rare: only when n > CSLOT*MCH*slot+MCH)
    }
}

extern "C" void kernel_launch(void* const* d_in, const int* in_sizes, int n_in,
                              void* d_out, int out_size, void* d_ws, size_t ws_size,
                              hipStream_t stream) {
    const float* x       = (const float*)d_in[0];
    const int*   task_id = (const int*)d_in[1];
    const float* W       = (const float*)d_in[2];
    float*       out     = (float*)d_out;

    dim3 grid(NTASK * 64 * CSLOT);
    dim3 block(BSZ);
    hipLaunchKernelGGL(cond_linear_kernel, grid, block, 0, stream,
                       x, task_id, W, out);
}

// Round 4
// 39.337 us; speedup vs baseline: 1.6972x; 1.1761x over previous
//
#include <hip/hip_runtime.h>

#define FIN   1024
#define FOUT2 1024
#define NTASK 20
#define BSZ   256
#define HOFF  (256 * 512)        // h output elements before logits

// Grid: NTASK * 64 blocks. Block -> (task, 16-output tile); wave -> 4 output rows.
// Ballot builds the stable sample list (1 KB LDS), then waves run independently:
// W rows held in registers (waves_per_eu(4,4) gives a 128-VGPR budget), x read
// straight from global (L1/L2-resident, shared by the block's 4 waves) with a
// 1-deep prefetch. Dot expression, lane mapping, butterfly order, and writes are
// bit-identical to the round-1/2/3 passing kernels.
__global__
__attribute__((amdgpu_flat_work_group_size(256, 256), amdgpu_waves_per_eu(4, 4)))
void cond_linear_kernel(const float* __restrict__ x,
                        const int* __restrict__ task_id,
                        const float* __restrict__ W,
                        float* __restrict__ out) {
    __shared__ int sh_ord[BSZ];
    __shared__ int wcnt[4];
    __shared__ int sh_n;

    const int tid  = threadIdx.x;
    const int lane = tid & 63;
    const int wv   = tid >> 6;
    const int t    = blockIdx.x >> 6;     // task id
    const int tile = blockIdx.x & 63;     // 64 tiles of 16 outputs
    const int o0   = tile * 16 + wv * 4;  // this wave's 4 output rows

    // ---- build this task's stable sample list (B == blockDim == 256) ----
    const int my_task = task_id[tid];
    const bool match = (my_task == t);
    const unsigned long long m64 = __ballot(match);
    if (lane == 0) wcnt[wv] = __popcll(m64);
    __syncthreads();
    int base = 0;
    #pragma unroll
    for (int w = 0; w < 4; ++w)
        if (w < wv) base += wcnt[w];
    if (match) {
        const int pos = base + __popcll(m64 & ((1ull << lane) - 1ull));
        sh_ord[pos] = tid;
    }
    if (tid == 0) sh_n = wcnt[0] + wcnt[1] + wcnt[2] + wcnt[3];
    __syncthreads();
    const int n = sh_n;
    if (n == 0) return;

    // ---- this wave's 4 W rows in registers (W read exactly once per block) ----
    const float* Wt = W + (size_t)t * (FOUT2 * FIN);
    float4 wr[4][4];
    #pragma unroll
    for (int r = 0; r < 4; ++r) {
        const float4* wp = (const float4*)(Wt + (size_t)(o0 + r) * FIN);
        #pragma unroll
        for (int p = 0; p < 4; ++p)
            wr[r][p] = wp[p * 64 + lane];
    }

    // ---- sample loop, 1-deep x prefetch, no LDS, no further syncs ----
    int s_cur = sh_ord[0];
    float4 xv_cur[4];
    {
        const float4* xp = (const float4*)(x + (size_t)s_cur * FIN);
        #pragma unroll
        for (int p = 0; p < 4; ++p)
            xv_cur[p] = xp[p * 64 + lane];
    }

    for (int i = 0; i < n; ++i) {
        const int s_nxt = sh_ord[(i + 1 < n) ? (i + 1) : i];
        float4 xv_nxt[4];
        {
            const float4* xp = (const float4*)(x + (size_t)s_nxt * FIN);
            #pragma unroll
            for (int p = 0; p < 4; ++p)
                xv_nxt[p] = xp[p * 64 + lane];
        }

        float v0 = 0.f, v1 = 0.f, v2 = 0.f, v3 = 0.f;
        #pragma unroll
        for (int p = 0; p < 4; ++p) {
            const float4 xv = xv_cur[p];
            v0 += wr[0][p].x * xv.x + wr[0][p].y * xv.y + wr[0][p].z * xv.z + wr[0][p].w * xv.w;
            v1 += wr[1][p].x * xv.x + wr[1][p].y * xv.y + wr[1][p].z * xv.z + wr[1][p].w * xv.w;
            v2 += wr[2][p].x * xv.x + wr[2][p].y * xv.y + wr[2][p].z * xv.z + wr[2][p].w * xv.w;
            v3 += wr[3][p].x * xv.x + wr[3][p].y * xv.y + wr[3][p].z * xv.z + wr[3][p].w * xv.w;
        }

        #pragma unroll
        for (int sh = 32; sh >= 1; sh >>= 1) {
            v0 += __shfl_xor(v0, sh, 64);
            v1 += __shfl_xor(v1, sh, 64);
            v2 += __shfl_xor(v2, sh, 64);
            v3 += __shfl_xor(v3, sh, 64);
        }
        if (lane == 0) {
            const int s = s_cur;
            float* lo = out + HOFF + (size_t)s * FOUT2 + o0;
            lo[0] = v0; lo[1] = v1; lo[2] = v2; lo[3] = v3;
            out[(size_t)s * (FOUT2 / 2) + (o0 >> 1)]     = (v0 >= v1) ? 1.0f : 0.0f;
            out[(size_t)s * (FOUT2 / 2) + (o0 >> 1) + 1] = (v2 >= v3) ? 1.0f : 0.0f;
        }

        s_cur = s_nxt;
        #pragma unroll
        for (int p = 0; p < 4; ++p)
            xv_cur[p] = xv_nxt[p];
    }
}

extern "C" void kernel_launch(void* const* d_in, const int* in_sizes, int n_in,
                              void* d_out, int out_size, void* d_ws, size_t ws_size,
                              hipStream_t stream) {
    const float* x       = (const float*)d_in[0];
    const int*   task_id = (const int*)d_in[1];
    const float* W       = (const float*)d_in[2];
    float*       out     = (float*)d_out;

    dim3 grid(NTASK * 64);
    dim3 block(BSZ);
    hipLaunchKernelGGL(cond_linear_kernel, grid, block, 0, stream,
                       x, task_id, W, out);
}